// Round 7
// baseline (517.214 us; speedup 1.0000x reference)
//
#include <hip/hip_runtime.h>
#include <hip/hip_bf16.h>

typedef unsigned short u16;
typedef __attribute__((ext_vector_type(8))) short short8;
typedef __attribute__((ext_vector_type(4))) float f32x4;

#define T_STEPS 10
#define NB 8
#define HH 64
#define WW 64
#define FF 64
#define NGATE 256
#define HP 66
#define PIX (NB*HH*WW)          // 32768
#define ROWCH 528               // 66 px * 8 chunks per padded row

__device__ __forceinline__ u16 f2bf(float f) {
    unsigned u = __float_as_uint(f);
    u += 0x7FFF + ((u >> 16) & 1);   // round-to-nearest-even
    return (u16)(u >> 16);
}
__device__ __forceinline__ float hsig(float x) {
    return fminf(fmaxf(0.2f * x + 0.5f, 0.0f), 1.0f);
}
__device__ __forceinline__ float ftanh(float x) {
    float e = __expf(2.0f * x);
    return 1.0f - 2.0f / (e + 1.0f);
}
__device__ __forceinline__ void gll16(const void* g, void* l) {
    __builtin_amdgcn_global_load_lds(
        (const __attribute__((address_space(1))) unsigned*)g,
        (__attribute__((address_space(3))) unsigned*)l, 16, 0, 0);
}

// Build B in MFMA-fragment-stream order, bf16:
//   stream[kc][fq][ks][g][lane][e]; value = W[kc*64+ks*32+quad*8+e][g*64+fq*16+l15]
__global__ void wtrans_kernel(const float* __restrict__ W0,
                              const float* __restrict__ W1,
                              u16* __restrict__ BS, int K) {
    int total = (K >> 6) << 14;
    for (int o = blockIdx.x * blockDim.x + threadIdx.x; o < total;
         o += gridDim.x * blockDim.x) {
        int e = o & 7, lane = (o >> 3) & 63, g = (o >> 9) & 3;
        int ks = (o >> 11) & 1, fq = (o >> 12) & 3, kc = o >> 14;
        int quad = lane >> 4, l15 = lane & 15;
        int n = g * 64 + fq * 16 + l15;
        int k = kc * 64 + ks * 32 + quad * 8 + e;
        float v = (k < 576) ? W0[k * NGATE + n] : W1[(k - 576) * NGATE + n];
        BS[o] = f2bf(v);
    }
}

// Fused dual-layer ConvLSTM tick, BARRIER-FREE K-loop.
// All h-rows a block needs (3 for role-0, 6 for role-1) are staged into LDS
// ONCE via global_load_lds (XOR-swizzled 16B chunks), one barrier, then the
// whole implicit-GEMM runs with zero barriers: waves drift freely, so B-load
// latency on one wave overlaps MFMA on others. B: direct from the global
// fragment stream (XCD-L2-resident). Role decode mixes roles per CU slot.
__global__ __launch_bounds__(256, 3)
void fused_step_kernel(const u16* __restrict__ h0_prev, u16* __restrict__ h0_new,
                       const u16* __restrict__ h1_prev, u16* __restrict__ h1_new,
                       const u16* __restrict__ B0S, const u16* __restrict__ B1S,
                       const float* __restrict__ x, const float* __restrict__ k0w,
                       const float* __restrict__ b0, const float* __restrict__ b1,
                       float* __restrict__ c0, float* __restrict__ c1,
                       float* __restrict__ oh0, float* __restrict__ oc0,
                       float* __restrict__ oh1, float* __restrict__ oc1,
                       int u) {
    int blk = blockIdx.x;
    int b = blk & 7;                 // batch == XCD (blockIdx % 8 round-robin)
    int k = blk >> 3;                // XCD-local index (-> CU k%32, slot k/32)
    int c = k & 31, s = k >> 5;
    int role = (c + s) & 1;          // alternate per CU slot -> 2+2 mix per CU
    int y = c + ((s >> 1) << 5);     // image row 0..63 (bijective per role)
    int pxb = b * 64 + y;
    if (role == 0 && u >= T_STEPS) return;
    if (role == 1 && u == 0) return;

    // Row r (r<3: h0 padded rows y..y+2; r>=3: h1 rows), 528 16B-chunks each.
    // LDS chunk q=r*528+px*8+w holds ch-block cb = w ^ (px&7)  (bank swizzle).
    __shared__ __align__(16) u16 sRows[3328 * 8];   // 13*256 chunks = 52 KB
    __shared__ float xs[3][WW + 2];

    int tid = threadIdx.x;
    int lane = tid & 63, fq = tid >> 6;
    int quad = lane >> 4, l15 = lane & 15;

    const u16* BS = role ? B1S : B0S;
    int nrows = role ? 6 : 3;
    int nstage = nrows * ROWCH;

    if (role == 0 && tid < 3 * (WW + 2)) {
        int dyi = tid / (WW + 2), xx = tid - dyi * (WW + 2);
        int yy = y + dyi - 1, col = xx - 1;
        float v = 0.0f;
        if (yy >= 0 && yy < HH && col >= 0 && col < WW)
            v = x[(((size_t)b * T_STEPS + u) * HH + yy) * WW + col];
        xs[dyi][xx] = v;
    }

    // ---- stage all rows (one-time), then ONE barrier ----
    for (int j = 0; j < 13; ++j) {
        int q = tid + j * 256;
        if (q < nstage) {
            int r = q / ROWCH, rem = q - r * ROWCH;
            int px = rem >> 3, cb = (rem & 7) ^ (px & 7);
            const u16* src = (r < 3) ? h0_prev : h1_prev;
            int grow = y + ((r < 3) ? r : r - 3);
            gll16(src + ((size_t)(b * HP + grow) * HP + px) * FF + cb * 8,
                  &sRows[(size_t)q * 8]);
        }
    }
    asm volatile("s_waitcnt vmcnt(0) lgkmcnt(0)\n\ts_barrier" ::: "memory");

    f32x4 acc[4][4];
#pragma unroll
    for (int mt = 0; mt < 4; ++mt)
#pragma unroll
        for (int g = 0; g < 4; ++g)
            acc[mt][g] = (f32x4){0.f, 0.f, 0.f, 0.f};

    // ---- barrier-free K-loop (fully unrolled per role) ----
#define TAP(KC, ROWBASE, DX)                                                  \
    {                                                                         \
        const u16* bp = BS + ((size_t)(KC) << 14) + (fq << 12) + lane * 8;    \
        short8 bF[8];                                                         \
        _Pragma("unroll")                                                     \
        for (int j = 0; j < 8; ++j)                                           \
            bF[j] = *(const short8*)(bp + ((size_t)j << 9));                  \
        _Pragma("unroll")                                                     \
        for (int ks = 0; ks < 2; ++ks) {                                      \
            short8 aF[4];                                                     \
            _Pragma("unroll")                                                 \
            for (int mt = 0; mt < 4; ++mt) {                                  \
                int px = mt * 16 + l15 + (DX) + 1;                            \
                int chunk = (ROWBASE) + px * 8 + ((ks * 4 + quad) ^ (px & 7));\
                aF[mt] = *(const short8*)&sRows[(size_t)chunk * 8];           \
            }                                                                 \
            _Pragma("unroll")                                                 \
            for (int mt = 0; mt < 4; ++mt)                                    \
                _Pragma("unroll")                                             \
                for (int g = 0; g < 4; ++g)                                   \
                    acc[mt][g] = __builtin_amdgcn_mfma_f32_16x16x32_bf16(     \
                        aF[mt], bF[ks * 4 + g], acc[mt][g], 0, 0, 0);         \
        }                                                                     \
    }

    if (role == 0) {
#pragma unroll
        for (int kc = 0; kc < 9; ++kc)
            TAP(kc, (kc / 3) * ROWCH, kc % 3 - 1);
    } else {
#pragma unroll
        for (int kc = 0; kc < 18; ++kc) {
            int t = (kc < 9) ? kc : kc - 9;
            int row = ((kc < 9) ? 0 : 3) + t / 3;
            TAP(kc, row * ROWCH, t % 3 - 1);
        }
    }

    // ---- epilogue: LSTM gate update (lane-local: f = fq*16+l15) ----
    const float* bias = role ? b1 : b0;
    float* cbuf = role ? c1 : c0;
    u16* hout = role ? h1_new : h0_new;
    int wo = role ? (u == T_STEPS) : (u == T_STEPS - 1);
    float* outh = role ? oh1 : oh0;
    float* outc = role ? oc1 : oc0;

    int f = fq * 16 + l15;
    float bi = bias[f], bff = bias[64 + f], bg = bias[128 + f], bo = bias[192 + f];
    float wk[4][9];
    if (role == 0) {
#pragma unroll
        for (int g = 0; g < 4; ++g)
#pragma unroll
            for (int tau = 0; tau < 9; ++tau)
                wk[g][tau] = k0w[tau * NGATE + g * 64 + f];
    }
#pragma unroll
    for (int mt = 0; mt < 4; ++mt) {
#pragma unroll
        for (int r = 0; r < 4; ++r) {
            int xcol = mt * 16 + quad * 4 + r;      // pixel x within the row
            size_t p = (size_t)pxb * 64 + xcol;     // global pixel
            float zi = acc[mt][0][r] + bi;
            float zf = acc[mt][1][r] + bff;
            float zg = acc[mt][2][r] + bg;
            float zo = acc[mt][3][r] + bo;
            if (role == 0) {   // fused layer-0 input conv, fp32 exact
#pragma unroll
                for (int tau = 0; tau < 9; ++tau) {
                    float xv = xs[tau / 3][xcol + tau % 3];
                    zi += xv * wk[0][tau];
                    zf += xv * wk[1][tau];
                    zg += xv * wk[2][tau];
                    zo += xv * wk[3][tau];
                }
            }
            float cold = cbuf[p * FF + f];
            float cn = hsig(zf) * cold + hsig(zi) * ftanh(zg);
            float hn = hsig(zo) * ftanh(cn);
            cbuf[p * FF + f] = cn;
            hout[(((size_t)(b * HP + y + 1)) * HP + (xcol + 1)) * FF + f] = f2bf(hn);
            if (wo) { outh[p * FF + f] = hn; outc[p * FF + f] = cn; }
        }
    }
}

extern "C" void kernel_launch(void* const* d_in, const int* in_sizes, int n_in,
                              void* d_out, int out_size, void* d_ws, size_t ws_size,
                              hipStream_t stream) {
    const float* x   = (const float*)d_in[0];
    const float* k0  = (const float*)d_in[1];
    const float* rk0 = (const float*)d_in[2];
    const float* b0  = (const float*)d_in[3];
    const float* k1  = (const float*)d_in[4];
    const float* rk1 = (const float*)d_in[5];
    const float* b1  = (const float*)d_in[6];
    float* out = (float*)d_out;

    char* ws = (char*)d_ws;
    const size_t HPAD_BYTES = (size_t)NB * HP * HP * FF * 2;  // 4,460,544
    const size_t C_BYTES    = (size_t)PIX * FF * 4;           // 8,388,608

    u16* h0p[2]; u16* h1p[2];
    h0p[0] = (u16*)(ws);
    h0p[1] = (u16*)(ws + HPAD_BYTES);
    h1p[0] = (u16*)(ws + 2 * HPAD_BYTES);
    h1p[1] = (u16*)(ws + 3 * HPAD_BYTES);
    float* c0 = (float*)(ws + 4 * HPAD_BYTES);
    float* c1 = (float*)(ws + 4 * HPAD_BYTES + C_BYTES);
    u16* B0S  = (u16*)(ws + 4 * HPAD_BYTES + 2 * C_BYTES);
    u16* B1S  = (u16*)(ws + 4 * HPAD_BYTES + 2 * C_BYTES + (size_t)9 * 16384 * 2);

    // Zero h (incl. halo == SAME padding) and c states; ws is poisoned 0xAA.
    hipMemsetAsync(ws, 0, 4 * HPAD_BYTES + 2 * C_BYTES, stream);

    wtrans_kernel<<<512, 256, 0, stream>>>(rk0, rk0, B0S, 576);
    wtrans_kernel<<<512, 256, 0, stream>>>(k1, rk1, B1S, 1152);

    float* oh0 = out;
    float* oc0 = out + (size_t)PIX * FF;
    float* oh1 = out + 2 * (size_t)PIX * FF;
    float* oc1 = out + 3 * (size_t)PIX * FF;

    // Tick u: layer-0 computes step u (reads h0[u-1] -> writes h0[u]);
    //         layer-1 computes step u-1 (reads h0[u-1], h1[u-2] -> h1[u-1]).
    for (int u = 0; u <= T_STEPS; ++u) {
        const u16* h0_prev = h0p[(u + 1) & 1];
        u16*       h0_new  = h0p[u & 1];
        const u16* h1_prev = h1p[u & 1];
        u16*       h1_new  = h1p[(u + 1) & 1];
        fused_step_kernel<<<1024, 256, 0, stream>>>(
            h0_prev, h0_new, h1_prev, h1_new, B0S, B1S,
            x, k0, b0, b1, c0, c1, oh0, oc0, oh1, oc1, u);
    }
}